// Round 8
// baseline (1268.254 us; speedup 1.0000x reference)
//
#include <hip/hip_runtime.h>
#include <hip/hip_bf16.h>

#define N_GRAPHS 64
#define TPAD 68     // padded LDS row stride (floats)
#define NT 16       // src tiles (src >> TSHIFT); tiles 13-15 empty for N=100k
#define TSHIFT 13   // 8192 nodes/tile -> 2MB of T per tile
#define NBW2 200    // dst nodes per bucket -> 500 buckets
#define WPB 8       // waves per bucket
#define NPW 25      // nodes per wave (8*25 = 200)
#define NKEY 3200   // keys per bucket: wl*400 + tile*25 + slot
#define NKEYP 3328  // padded to 13*256

// ---------------- bucket-level histogram (bucket = dst/200) ----------------

#define EBH 8192
__global__ void bucket_hist_kernel(const int* __restrict__ dst, int* __restrict__ bcnt,
                                   int E, int nbuck) {
    __shared__ int lh[512];
    const int tid = threadIdx.x;
    for (int i = tid; i < 512; i += 256) lh[i] = 0;
    __syncthreads();
    const int e0 = blockIdx.x * EBH;
    const int e1 = min(e0 + EBH, E);
    for (int e = e0 + tid; e < e1; e += 256)
        atomicAdd(&lh[dst[e] / NBW2], 1);
    __syncthreads();
    for (int i = tid; i < nbuck; i += 256) {
        int c = lh[i];
        if (c) atomicAdd(&bcnt[i], c);
    }
}

// exclusive scan of bucket counts (nbuck <= 512), seed bucket cursors
__global__ void bucket_scan_kernel(const int* __restrict__ bcnt, int* __restrict__ bbase,
                                   int* __restrict__ bcur, int nbuck) {
    __shared__ int sh[512];
    const int tid = threadIdx.x;
    int v = (tid < nbuck) ? bcnt[tid] : 0;
    sh[tid] = v;
    __syncthreads();
    for (int off = 1; off < 512; off <<= 1) {
        int t = (tid >= off) ? sh[tid - off] : 0;
        __syncthreads();
        sh[tid] += t;
        __syncthreads();
    }
    if (tid < nbuck) { int e = sh[tid] - v; bbase[tid] = e; bcur[tid] = e; }
    if (tid == nbuck - 1) bbase[nbuck] = sh[tid];
}

// ---------------- binned scatter: packed edge = dloc<<24 | src ----------------

#define EBC 4096
__global__ void binscatter_kernel(const int* __restrict__ src, const int* __restrict__ dst,
                                  int* __restrict__ bcur, unsigned* __restrict__ binned,
                                  int E, int nbuck) {
    __shared__ int lhist[512];
    __shared__ int lbase[512];
    const int tid = threadIdx.x;
    const int e0 = blockIdx.x * EBC;
    const int e1 = min(e0 + EBC, E);
    for (int i = tid; i < 512; i += 256) lhist[i] = 0;
    __syncthreads();
    for (int e = e0 + tid; e < e1; e += 256) atomicAdd(&lhist[dst[e] / NBW2], 1);
    __syncthreads();
    for (int i = tid; i < nbuck; i += 256) {
        int c = lhist[i];
        lbase[i] = (c > 0) ? atomicAdd(&bcur[i], c) : 0;
        lhist[i] = 0;
    }
    __syncthreads();
    for (int e = e0 + tid; e < e1; e += 256) {
        int d = dst[e];
        int b = d / NBW2;
        int off = atomicAdd(&lhist[b], 1);
        binned[lbase[b] + off] = ((unsigned)(d - b * NBW2) << 24) | (unsigned)src[e];
    }
}

// ---------------- per-bucket build: deg/dis/Xs, (wave,tile,slot)-ordered col3,
//                  per-(wave,tile,slot) counts cnt8, per-wave start wstart ----------------

__global__ void build_stream_kernel(const unsigned* __restrict__ binned, const int* __restrict__ bbase,
                                    const float* __restrict__ x, float* __restrict__ dis_g,
                                    float* __restrict__ Xs, int* __restrict__ col3,
                                    unsigned char* __restrict__ cnt8, int* __restrict__ wstart,
                                    int n) {
    __shared__ int ck[NKEYP];
    __shared__ int wsum[4];
    const int b = blockIdx.x;
    const int node_base = b * NBW2;
    const int tid = threadIdx.x;
    for (int i = tid; i < NKEYP; i += 256) ck[i] = 0;
    __syncthreads();
    const int e0 = bbase[b], e1 = bbase[b + 1];
    for (int e = e0 + tid; e < e1; e += 256) {
        unsigned v = binned[e];
        int dloc = v >> 24;
        int t = (int)((v & 0xFFFFFFu) >> TSHIFT);
        atomicAdd(&ck[(dloc / NPW) * 400 + t * 25 + (dloc % NPW)], 1);
    }
    __syncthreads();
    // degrees -> dis, Xs = dis*x ; snapshot counts -> cnt8
    if (tid < NBW2) {
        int node = node_base + tid;
        if (node < n) {
            int wl = tid / NPW, k = tid % NPW;
            int deg = 0;
            #pragma unroll
            for (int t = 0; t < NT; ++t) deg += ck[wl * 400 + t * 25 + k];
            float d = rsqrtf((float)deg + 1.0f);
            dis_g[node] = d;
            float4 xv = *(const float4*)&x[node * 4];
            *(float4*)&Xs[node * 4] = make_float4(d * xv.x, d * xv.y, d * xv.z, d * xv.w);
        }
    }
    for (int i = tid; i < NKEY; i += 256) cnt8[(size_t)b * NKEY + i] = (unsigned char)ck[i];
    __syncthreads();
    // exclusive scan over 3328 keys: 13 per thread
    const int base_i = tid * 13;
    int lsum = 0;
    #pragma unroll
    for (int j = 0; j < 13; ++j) lsum += ck[base_i + j];
    const int lane = tid & 63, wid = tid >> 6;
    int s = lsum;
    #pragma unroll
    for (int off = 1; off < 64; off <<= 1) {
        int t = __shfl_up(s, off);
        if (lane >= off) s += t;
    }
    if (lane == 63) wsum[wid] = s;
    __syncthreads();
    int woff = 0;
    for (int w = 0; w < wid; ++w) woff += wsum[w];
    int run = e0 + woff + s - lsum;
    #pragma unroll
    for (int j = 0; j < 13; ++j) { int c = ck[base_i + j]; ck[base_i + j] = run; run += c; }
    __syncthreads();
    if (tid < WPB) wstart[b * WPB + tid] = ck[tid * 400];
    __syncthreads();
    // scatter src into (wave,tile,slot)-ordered col3
    for (int e = e0 + tid; e < e1; e += 256) {
        unsigned v = binned[e];
        int dloc = v >> 24;
        int srcv = (int)(v & 0xFFFFFFu);
        int t = srcv >> TSHIFT;
        int p = atomicAdd(&ck[(dloc / NPW) * 400 + t * 25 + (dloc % NPW)], 1);
        col3[p] = srcv;
    }
}

// ---------------- persistent phased stream-gather aggregation ----------------
// wave w owns nodes [w*25, w*25+25), edges contiguous in col3 ordered (tile, slot).
// Counted inner loops (cnt8) -> no per-edge branch, pipelined loads, register acc.
// All ~1000 blocks resident (LDS=0, <=128 VGPR) -> chip-wide tile phases align,
// each phase gathers from a 2MB L2-resident slice of t.

template <int F, bool RELU, bool BIAS>
__global__ __launch_bounds__(256, 4)
void agg_stream_kernel(const float* __restrict__ t, const int* __restrict__ col3,
                       const unsigned char* __restrict__ cnt8, const int* __restrict__ wstart,
                       const float* __restrict__ dis, const float* __restrict__ bias,
                       float* __restrict__ out, int n, int nwave) {
    const int tid = threadIdx.x;
    const int w = blockIdx.x * 4 + (tid >> 6);
    if (w >= nwave) return;
    const int lane = tid & 63;
    const int fl = lane & (F - 1);
    float acc[NPW];
    #pragma unroll
    for (int k = 0; k < NPW; ++k) acc[k] = 0.0f;
    int cur = wstart[w];
    const size_t cbase = (size_t)w * 400;
    for (int tp = 0; tp < NT; ++tp) {
        int cntv = (lane < NPW) ? (int)cnt8[cbase + tp * 25 + lane] : 0;
        #pragma unroll
        for (int k = 0; k < NPW; ++k) {
            const int c = __shfl(cntv, k);
            for (int j = 0; j < c; ++j) {
                int s = col3[cur + j];
                acc[k] += t[(size_t)s * F + fl];
            }
            cur += c;
        }
    }
    const int nodeb = w * NPW;
    const float bv = BIAS ? bias[fl] : 0.0f;
    #pragma unroll
    for (int k = 0; k < NPW; ++k) {
        int i = nodeb + k;
        if (i < n && lane < F) {
            float d = dis[i];
            float r = d * (acc[k] + t[(size_t)i * F + fl]) + bv;
            if (RELU) r = fmaxf(r, 0.0f);
            out[(size_t)i * F + fl] = r;
        }
    }
}

// ---------------- fused layer-1 transform + layer-2 pre-transform ----------------
// T[i] = dis[i] * ( relu(aggX[i] @ W1 + b1) @ W2 )

__global__ void fused_l1_kernel(const float* __restrict__ aggX, const float* __restrict__ W1,
                                const float* __restrict__ b1, const float* __restrict__ W2,
                                const float* __restrict__ dis, float* __restrict__ t, int n) {
    __shared__ float W1s[256];
    __shared__ float b1s[64];
    __shared__ float Wt[64 * TPAD];
    __shared__ float Hs[64 * TPAD];
    const int tid = threadIdx.x;
    const int base = blockIdx.x * 64;
    if (tid < 256) W1s[tid] = W1[tid];
    if (tid < 64) b1s[tid] = b1[tid];
    for (int idx = tid; idx < 4096; idx += 256) {
        int k = idx >> 6, f = idx & 63;
        Wt[f * TPAD + k] = W2[idx];
    }
    __syncthreads();
    for (int idx = tid; idx < 4096; idx += 256) {
        int nn = idx >> 6, k = idx & 63;
        int node = base + nn;
        float v = 0.0f;
        if (node < n) {
            float4 a = *(const float4*)&aggX[node * 4];
            v = fmaxf(a.x * W1s[k] + a.y * W1s[64 + k] + a.z * W1s[128 + k] + a.w * W1s[192 + k]
                      + b1s[k], 0.0f);
        }
        Hs[nn * TPAD + k] = v;
    }
    __syncthreads();
    const int tf = tid & 15;
    const int tn = tid >> 4;
    float acc[4][4] = {};
    for (int k = 0; k < 64; k += 4) {
        float4 w4[4], h4[4];
        #pragma unroll
        for (int ff = 0; ff < 4; ++ff) w4[ff] = *(const float4*)&Wt[(tf * 4 + ff) * TPAD + k];
        #pragma unroll
        for (int nn = 0; nn < 4; ++nn) h4[nn] = *(const float4*)&Hs[(tn * 4 + nn) * TPAD + k];
        #pragma unroll
        for (int nn = 0; nn < 4; ++nn)
            #pragma unroll
            for (int ff = 0; ff < 4; ++ff)
                acc[nn][ff] += h4[nn].x * w4[ff].x + h4[nn].y * w4[ff].y +
                               h4[nn].z * w4[ff].z + h4[nn].w * w4[ff].w;
    }
    #pragma unroll
    for (int nn = 0; nn < 4; ++nn) {
        int node = base + tn * 4 + nn;
        if (node < n) {
            float d = dis[node];
            float4 o = make_float4(d * acc[nn][0], d * acc[nn][1], d * acc[nn][2], d * acc[nn][3]);
            *(float4*)&t[node * 64 + tf * 4] = o;
        }
    }
}

// ---------------- W3 transform: T32[i] = dis[i] * (H[i] @ W3) ----------------

__global__ void transform64_32_kernel(const float* __restrict__ h, const float* __restrict__ W,
                                      const float* __restrict__ dis, float* __restrict__ t, int n) {
    __shared__ float Wt[32 * TPAD];
    __shared__ float Hs[128 * TPAD];
    const int tid = threadIdx.x;
    const int base = blockIdx.x * 128;
    for (int idx = tid; idx < 2048; idx += 256) {
        int k = idx >> 5, f = idx & 31;
        Wt[f * TPAD + k] = W[idx];
    }
    for (int idx = tid; idx < 8192; idx += 256) {
        int nn = idx >> 6, k = idx & 63;
        int node = base + nn;
        Hs[nn * TPAD + k] = (node < n) ? h[node * 64 + k] : 0.0f;
    }
    __syncthreads();
    const int tf = tid & 7;
    const int tn = tid >> 3;
    float acc[4][4] = {};
    for (int k = 0; k < 64; k += 4) {
        float4 w4[4], h4[4];
        #pragma unroll
        for (int ff = 0; ff < 4; ++ff) w4[ff] = *(const float4*)&Wt[(tf * 4 + ff) * TPAD + k];
        #pragma unroll
        for (int nn = 0; nn < 4; ++nn) h4[nn] = *(const float4*)&Hs[(tn * 4 + nn) * TPAD + k];
        #pragma unroll
        for (int nn = 0; nn < 4; ++nn)
            #pragma unroll
            for (int ff = 0; ff < 4; ++ff)
                acc[nn][ff] += h4[nn].x * w4[ff].x + h4[nn].y * w4[ff].y +
                               h4[nn].z * w4[ff].z + h4[nn].w * w4[ff].w;
    }
    #pragma unroll
    for (int nn = 0; nn < 4; ++nn) {
        int node = base + tn * 4 + nn;
        if (node < n) {
            float d = dis[node];
            float4 o = make_float4(d * acc[nn][0], d * acc[nn][1], d * acc[nn][2], d * acc[nn][3]);
            *(float4*)&t[node * 32 + tf * 4] = o;
        }
    }
}

// ---------------- readout ----------------

__device__ __forceinline__ unsigned mapf(float v) {
    unsigned u = __float_as_uint(v);
    return u ^ ((u & 0x80000000u) ? 0xFFFFFFFFu : 0x80000000u);
}

#define MAPPED_NEG_INF 0x007FFFFFu

__global__ void init_readout_kernel(float* __restrict__ gsum, unsigned* __restrict__ gmax,
                                    int* __restrict__ gcnt) {
    int idx = blockIdx.x * blockDim.x + threadIdx.x;
    if (idx < N_GRAPHS * 32) { gsum[idx] = 0.0f; gmax[idx] = MAPPED_NEG_INF; }
    if (idx < N_GRAPHS) gcnt[idx] = 0;
}

#define R_CHUNK 512
__global__ void readout_kernel(const float* __restrict__ emb, const int* __restrict__ batch,
                               float* __restrict__ gsum, unsigned* __restrict__ gmax,
                               int* __restrict__ gcnt, int n) {
    __shared__ float ssum[N_GRAPHS * 32];
    __shared__ unsigned smax[N_GRAPHS * 32];
    __shared__ int scnt[N_GRAPHS];
    const int tid = threadIdx.x;
    for (int idx = tid; idx < N_GRAPHS * 32; idx += 256) { ssum[idx] = 0.0f; smax[idx] = MAPPED_NEG_INF; }
    if (tid < N_GRAPHS) scnt[tid] = 0;
    __syncthreads();
    const int lane = tid & 31, grp = tid >> 5;
    const int start = blockIdx.x * R_CHUNK;
    const int end = min(start + R_CHUNK, n);
    for (int i = start + grp; i < end; i += 8) {
        int g = batch[i];
        float v = emb[i * 32 + lane];
        atomicAdd(&ssum[g * 32 + lane], v);
        atomicMax(&smax[g * 32 + lane], mapf(v));
        if (lane == 0) atomicAdd(&scnt[g], 1);
    }
    __syncthreads();
    for (int idx = tid; idx < N_GRAPHS * 32; idx += 256) {
        int g = idx >> 5;
        if (scnt[g] > 0) {
            atomicAdd(&gsum[idx], ssum[idx]);
            atomicMax(&gmax[idx], smax[idx]);
        }
    }
    if (tid < N_GRAPHS && scnt[tid] > 0) atomicAdd(&gcnt[tid], scnt[tid]);
}

__global__ void finalize_kernel(const float* __restrict__ gsum, const unsigned* __restrict__ gmax,
                                const int* __restrict__ gcnt, float* __restrict__ out) {
    int idx = blockIdx.x * blockDim.x + threadIdx.x;
    if (idx >= N_GRAPHS * 32) return;
    int g = idx >> 5, f = idx & 31;
    float c = fmaxf((float)gcnt[g], 1.0f);
    out[g * 64 + f] = gsum[idx] / c;
    unsigned u = gmax[idx];
    unsigned bits = (u & 0x80000000u) ? (u ^ 0x80000000u) : ~u;
    out[g * 64 + 32 + f] = __uint_as_float(bits);
}

// ---------------- launch ----------------

extern "C" void kernel_launch(void* const* d_in, const int* in_sizes, int n_in,
                              void* d_out, int out_size, void* d_ws, size_t ws_size,
                              hipStream_t stream) {
    const float* x  = (const float*)d_in[0];
    const float* W1 = (const float*)d_in[1];
    const float* b1 = (const float*)d_in[2];
    const float* W2 = (const float*)d_in[3];
    const float* b2 = (const float*)d_in[4];
    const float* W3 = (const float*)d_in[5];
    const float* b3 = (const float*)d_in[6];
    const int* edge_index = (const int*)d_in[7];
    const int* batch = (const int*)d_in[8];
    float* out = (float*)d_out;

    const int N = in_sizes[0] / 4;
    const int E = in_sizes[7] / 2;
    const int* src = edge_index;
    const int* dst = edge_index + E;
    const int nbuck = (N + NBW2 - 1) / NBW2;   // 500 for N=100000
    const int nwave = nbuck * WPB;             // 4000
    const int gstream = (nwave + 3) / 4;       // 1000 blocks, all resident

    // workspace carve-up (256B aligned); total ~66 MB
    char* p = (char*)d_ws;
    auto alloc = [&](size_t bytes) { void* r = (void*)p; p += (bytes + 255) & ~(size_t)255; return r; };
    float*         dis    = (float*)alloc((size_t)N * 4);
    int*           col3   = (int*)alloc((size_t)E * 4);
    unsigned char* cnt8   = (unsigned char*)alloc((size_t)nbuck * NKEY);
    int*           wstart = (int*)alloc((size_t)nwave * 4);
    float*         T      = (float*)alloc((size_t)N * 64 * 4);
    float*         H      = (float*)alloc((size_t)N * 64 * 4);
    int*           bcnt   = (int*)alloc((size_t)512 * 4);
    int*           bbase  = (int*)alloc((size_t)513 * 4);
    int*           bcur   = (int*)alloc((size_t)512 * 4);
    float*         gsum   = (float*)alloc((size_t)N_GRAPHS * 32 * 4);
    unsigned*      gmax   = (unsigned*)alloc((size_t)N_GRAPHS * 32 * 4);
    int*           gcnt   = (int*)alloc((size_t)N_GRAPHS * 4);
    // aliases (lifetimes disjoint, kernels stream-ordered):
    unsigned* binned = (unsigned*)T;           // consumed by build before fused_l1 writes T
    float*    Xs     = H;                      // dead once T written
    float*    aggX   = H + (size_t)N * 4;      // dead once T written
    float*    T32    = T;                      // written after T(64) dead
    float*    H32    = H;                      // written after H(64) dead
    (void)ws_size; (void)n_in; (void)out_size;

    // CSR build: bucket-binned scatter, then per-bucket (wave,tile,slot) sort
    hipMemsetAsync(bcnt, 0, 512 * 4, stream);
    bucket_hist_kernel<<<(E + EBH - 1) / EBH, 256, 0, stream>>>(dst, bcnt, E, nbuck);
    bucket_scan_kernel<<<1, 512, 0, stream>>>(bcnt, bbase, bcur, nbuck);
    binscatter_kernel<<<(E + EBC - 1) / EBC, 256, 0, stream>>>(src, dst, bcur, binned, E, nbuck);
    build_stream_kernel<<<nbuck, 256, 0, stream>>>(binned, bbase, x, dis, Xs, col3, cnt8, wstart, N);

    // layer 1: phased stream-aggregate Xs (4-dim) -> aggX, then fused transform -> T
    agg_stream_kernel<4, false, false><<<gstream, 256, 0, stream>>>(Xs, col3, cnt8, wstart, dis, b1, aggX, N, nwave);
    fused_l1_kernel<<<(N + 63) / 64, 256, 0, stream>>>(aggX, W1, b1, W2, dis, T, N);
    // layer 2: phased stream-aggregate T (64-dim) + relu + b2 -> H
    agg_stream_kernel<64, true, true><<<gstream, 256, 0, stream>>>(T, col3, cnt8, wstart, dis, b2, H, N, nwave);
    // W3: T32 = dis * (H @ W3)
    transform64_32_kernel<<<(N + 127) / 128, 256, 0, stream>>>(H, W3, dis, T32, N);
    // layer 3: phased stream-aggregate T32 (32-dim) + b3 -> H32 (= emb)
    agg_stream_kernel<32, false, true><<<gstream, 256, 0, stream>>>(T32, col3, cnt8, wstart, dis, b3, H32, N, nwave);

    // readout
    init_readout_kernel<<<(N_GRAPHS * 32 + 255) / 256, 256, 0, stream>>>(gsum, gmax, gcnt);
    readout_kernel<<<(N + R_CHUNK - 1) / R_CHUNK, 256, 0, stream>>>(H32, batch, gsum, gmax, gcnt, N);
    finalize_kernel<<<(N_GRAPHS * 32 + 255) / 256, 256, 0, stream>>>(gsum, gmax, gcnt, out);
}

// Round 9
// 557.915 us; speedup vs baseline: 2.2732x; 2.2732x over previous
//
#include <hip/hip_runtime.h>
#include <hip/hip_bf16.h>

#define N_GRAPHS 64
#define TPAD 68     // padded LDS row stride (floats)
#define NT 16       // src tiles (src >> TSHIFT); tiles 13-15 empty for N=100k
#define TSHIFT 13   // 8192 nodes/tile -> 2MB of gather source per tile

// ---------------- bucket-level histogram (bucket = dst>>8, 256 nodes) ----------------

#define EBH 8192
__global__ void bucket_hist_kernel(const int* __restrict__ dst, int* __restrict__ bcnt,
                                   int E, int nbuck) {
    __shared__ int lh[512];
    const int tid = threadIdx.x;
    for (int i = tid; i < 512; i += 256) lh[i] = 0;
    __syncthreads();
    const int e0 = blockIdx.x * EBH;
    const int e1 = min(e0 + EBH, E);
    for (int e = e0 + tid; e < e1; e += 256)
        atomicAdd(&lh[((unsigned)dst[e]) >> 8], 1);
    __syncthreads();
    for (int i = tid; i < nbuck; i += 256) {
        int c = lh[i];
        if (c) atomicAdd(&bcnt[i], c);
    }
}

__global__ void bucket_scan_kernel(const int* __restrict__ bcnt, int* __restrict__ bbase,
                                   int* __restrict__ bcur, int nbuck) {
    __shared__ int sh[512];
    const int tid = threadIdx.x;
    int v = (tid < nbuck) ? bcnt[tid] : 0;
    sh[tid] = v;
    __syncthreads();
    for (int off = 1; off < 512; off <<= 1) {
        int t = (tid >= off) ? sh[tid - off] : 0;
        __syncthreads();
        sh[tid] += t;
        __syncthreads();
    }
    if (tid < nbuck) { int e = sh[tid] - v; bbase[tid] = e; bcur[tid] = e; }
    if (tid == nbuck - 1) bbase[nbuck] = sh[tid];
}

// ---------------- binned scatter: packed edge = dloc<<24 | src ----------------

#define EBC 4096
__global__ void binscatter_kernel(const int* __restrict__ src, const int* __restrict__ dst,
                                  int* __restrict__ bcur, unsigned* __restrict__ binned,
                                  int E, int nbuck) {
    __shared__ int lhist[512];
    __shared__ int lbase[512];
    const int tid = threadIdx.x;
    const int e0 = blockIdx.x * EBC;
    const int e1 = min(e0 + EBC, E);
    for (int i = tid; i < 512; i += 256) lhist[i] = 0;
    __syncthreads();
    for (int e = e0 + tid; e < e1; e += 256) atomicAdd(&lhist[((unsigned)dst[e]) >> 8], 1);
    __syncthreads();
    for (int i = tid; i < nbuck; i += 256) {
        int c = lhist[i];
        lbase[i] = (c > 0) ? atomicAdd(&bcur[i], c) : 0;
        lhist[i] = 0;
    }
    __syncthreads();
    for (int e = e0 + tid; e < e1; e += 256) {
        int d = dst[e];
        int b = ((unsigned)d) >> 8;
        int off = atomicAdd(&lhist[b], 1);
        binned[lbase[b] + off] = ((unsigned)(d & 255) << 24) | (unsigned)src[e];
    }
}

// ---------------- per-bucket build: (wave,tile,slot)-sorted col3, cnt16, wstart,
//                  degrees -> dis, Xs = dis*x ----------------
// key = (dloc>>5)*512 + tile*32 + (dloc&31);  8 waves x 32 slots per bucket

__global__ void build_sorted_kernel(const unsigned* __restrict__ binned, const int* __restrict__ bbase,
                                    const float* __restrict__ x, float* __restrict__ dis_g,
                                    float* __restrict__ Xs, int* __restrict__ col3,
                                    unsigned short* __restrict__ cnt16, int* __restrict__ wstart,
                                    int n) {
    __shared__ int ck[4096];
    __shared__ int wsum[4];
    const int b = blockIdx.x;
    const int node_base = b << 8;
    const int tid = threadIdx.x;
    for (int i = tid; i < 4096; i += 256) ck[i] = 0;
    __syncthreads();
    const int e0 = bbase[b], e1 = bbase[b + 1];
    for (int e = e0 + tid; e < e1; e += 256) {
        unsigned v = binned[e];
        int dloc = v >> 24;
        int tt = (int)((v & 0xFFFFFFu) >> TSHIFT);
        atomicAdd(&ck[(dloc >> 5) * 512 + tt * 32 + (dloc & 31)], 1);
    }
    __syncthreads();
    // degrees -> dis, Xs
    {
        int node = node_base + tid;
        if (node < n) {
            int w2 = tid >> 5, sl = tid & 31;
            int deg = 0;
            #pragma unroll
            for (int tt = 0; tt < NT; ++tt) deg += ck[w2 * 512 + tt * 32 + sl];
            float d = rsqrtf((float)deg + 1.0f);
            dis_g[node] = d;
            float4 xv = *(const float4*)&x[node * 4];
            *(float4*)&Xs[node * 4] = make_float4(d * xv.x, d * xv.y, d * xv.z, d * xv.w);
        }
    }
    // per-(wave,tile) totals
    if (tid < 128) {
        int w2 = tid >> 4, tt = tid & 15;
        int s = 0;
        #pragma unroll
        for (int sl = 0; sl < 32; ++sl) s += ck[w2 * 512 + tt * 32 + sl];
        cnt16[(size_t)(b * 8 + w2) * NT + tt] = (unsigned short)s;
    }
    __syncthreads();
    // exclusive scan of ck (4096 keys, 16/thread) -> global col3 offsets (base e0)
    const int base_i = tid * 16;
    int lsum = 0;
    #pragma unroll
    for (int j = 0; j < 16; ++j) lsum += ck[base_i + j];
    const int lane = tid & 63, wid = tid >> 6;
    int s = lsum;
    #pragma unroll
    for (int off = 1; off < 64; off <<= 1) {
        int t = __shfl_up(s, off);
        if (lane >= off) s += t;
    }
    if (lane == 63) wsum[wid] = s;
    __syncthreads();
    int woff = 0;
    for (int w = 0; w < wid; ++w) woff += wsum[w];
    int run = e0 + woff + s - lsum;
    #pragma unroll
    for (int j = 0; j < 16; ++j) { int c = ck[base_i + j]; ck[base_i + j] = run; run += c; }
    __syncthreads();
    if (tid < 8) wstart[b * 8 + tid] = ck[tid * 512];
    __syncthreads();
    // scatter (keep packed dloc<<24|src; agg uses slot = (v>>24)&31)
    for (int e = e0 + tid; e < e1; e += 256) {
        unsigned v = binned[e];
        int dloc = v >> 24;
        int tt = (int)((v & 0xFFFFFFu) >> TSHIFT);
        int p = atomicAdd(&ck[(dloc >> 5) * 512 + tt * 32 + (dloc & 31)], 1);
        col3[p] = (int)v;
    }
}

// ---------------- phase-aligned aggregation, wave-private LDS accumulators ----------------
// 782 blocks x 4 waves, all resident (32KB LDS -> 4 blocks/CU). Wave owns 32 nodes:
// acc[slot][f] owned by lane f (no sync, no atomics). Edges contiguous per (wave,tile),
// chip-wide tile phases align -> gathers hit a 2MB L2-resident slice per phase.
// out = [relu]( dis_i * (acc + t_self) + [bias] )

template <int F, bool RELU, bool BIAS>
__global__ __launch_bounds__(256, 4)
void agg_phase_kernel(const float* __restrict__ t, const int* __restrict__ col3,
                      const unsigned short* __restrict__ cnt16, const int* __restrict__ wstart,
                      const float* __restrict__ dis, const float* __restrict__ bias,
                      float* __restrict__ out, int n, int nwave) {
    __shared__ float accs[4][32 * F];
    const int tid = threadIdx.x;
    const int wl = tid >> 6, lane = tid & 63;
    float* acc = accs[wl];
    for (int i = lane; i < 32 * F; i += 64) acc[i] = 0.0f;
    const int gw = blockIdx.x * 4 + wl;
    if (gw < nwave) {
        int cur = wstart[gw];
        for (int tp = 0; tp < NT; ++tp) {
            const int cnt = (int)cnt16[(size_t)gw * NT + tp];
            int done = 0;
            while (done < cnt) {
                const int m = min(64, cnt - done);
                const unsigned pk = (lane < m) ? (unsigned)col3[cur + done + lane] : 0u;
                int jj = 0;
                for (; jj + 8 <= m; jj += 8) {
                    unsigned v0 = __shfl(pk, jj + 0), v1 = __shfl(pk, jj + 1);
                    unsigned v2 = __shfl(pk, jj + 2), v3 = __shfl(pk, jj + 3);
                    unsigned v4 = __shfl(pk, jj + 4), v5 = __shfl(pk, jj + 5);
                    unsigned v6 = __shfl(pk, jj + 6), v7 = __shfl(pk, jj + 7);
                    if (lane < F) {
                        float x0 = t[(size_t)(v0 & 0xFFFFFFu) * F + lane];
                        float x1 = t[(size_t)(v1 & 0xFFFFFFu) * F + lane];
                        float x2 = t[(size_t)(v2 & 0xFFFFFFu) * F + lane];
                        float x3 = t[(size_t)(v3 & 0xFFFFFFu) * F + lane];
                        float x4 = t[(size_t)(v4 & 0xFFFFFFu) * F + lane];
                        float x5 = t[(size_t)(v5 & 0xFFFFFFu) * F + lane];
                        float x6 = t[(size_t)(v6 & 0xFFFFFFu) * F + lane];
                        float x7 = t[(size_t)(v7 & 0xFFFFFFu) * F + lane];
                        acc[((v0 >> 24) & 31) * F + lane] += x0;
                        acc[((v1 >> 24) & 31) * F + lane] += x1;
                        acc[((v2 >> 24) & 31) * F + lane] += x2;
                        acc[((v3 >> 24) & 31) * F + lane] += x3;
                        acc[((v4 >> 24) & 31) * F + lane] += x4;
                        acc[((v5 >> 24) & 31) * F + lane] += x5;
                        acc[((v6 >> 24) & 31) * F + lane] += x6;
                        acc[((v7 >> 24) & 31) * F + lane] += x7;
                    }
                }
                for (; jj < m; ++jj) {
                    unsigned v = __shfl(pk, jj);
                    if (lane < F)
                        acc[((v >> 24) & 31) * F + lane] += t[(size_t)(v & 0xFFFFFFu) * F + lane];
                }
                done += m;
            }
            cur += cnt;
        }
        // epilogue
        const int nodeb = gw * 32;
        const float bv = (BIAS && lane < F) ? bias[lane] : 0.0f;
        for (int k = 0; k < 32; ++k) {
            int i = nodeb + k;
            if (i < n && lane < F) {
                float d = dis[i];
                float r = d * (acc[k * F + lane] + t[(size_t)i * F + lane]) + bv;
                if (RELU) r = fmaxf(r, 0.0f);
                out[(size_t)i * F + lane] = r;
            }
        }
    }
}

// ---------------- fused layer-1 transform + layer-2 pre-transform ----------------
// T[i] = dis[i] * ( relu(aggX[i] @ W1 + b1) @ W2 )

__global__ void fused_l1_kernel(const float* __restrict__ aggX, const float* __restrict__ W1,
                                const float* __restrict__ b1, const float* __restrict__ W2,
                                const float* __restrict__ dis, float* __restrict__ t, int n) {
    __shared__ float W1s[256];
    __shared__ float b1s[64];
    __shared__ float Wt[64 * TPAD];
    __shared__ float Hs[64 * TPAD];
    const int tid = threadIdx.x;
    const int base = blockIdx.x * 64;
    if (tid < 256) W1s[tid] = W1[tid];
    if (tid < 64) b1s[tid] = b1[tid];
    for (int idx = tid; idx < 4096; idx += 256) {
        int k = idx >> 6, f = idx & 63;
        Wt[f * TPAD + k] = W2[idx];
    }
    __syncthreads();
    for (int idx = tid; idx < 4096; idx += 256) {
        int nn = idx >> 6, k = idx & 63;
        int node = base + nn;
        float v = 0.0f;
        if (node < n) {
            float4 a = *(const float4*)&aggX[node * 4];
            v = fmaxf(a.x * W1s[k] + a.y * W1s[64 + k] + a.z * W1s[128 + k] + a.w * W1s[192 + k]
                      + b1s[k], 0.0f);
        }
        Hs[nn * TPAD + k] = v;
    }
    __syncthreads();
    const int tf = tid & 15;
    const int tn = tid >> 4;
    float acc[4][4] = {};
    for (int k = 0; k < 64; k += 4) {
        float4 w4[4], h4[4];
        #pragma unroll
        for (int ff = 0; ff < 4; ++ff) w4[ff] = *(const float4*)&Wt[(tf * 4 + ff) * TPAD + k];
        #pragma unroll
        for (int nn = 0; nn < 4; ++nn) h4[nn] = *(const float4*)&Hs[(tn * 4 + nn) * TPAD + k];
        #pragma unroll
        for (int nn = 0; nn < 4; ++nn)
            #pragma unroll
            for (int ff = 0; ff < 4; ++ff)
                acc[nn][ff] += h4[nn].x * w4[ff].x + h4[nn].y * w4[ff].y +
                               h4[nn].z * w4[ff].z + h4[nn].w * w4[ff].w;
    }
    #pragma unroll
    for (int nn = 0; nn < 4; ++nn) {
        int node = base + tn * 4 + nn;
        if (node < n) {
            float d = dis[node];
            float4 o = make_float4(d * acc[nn][0], d * acc[nn][1], d * acc[nn][2], d * acc[nn][3]);
            *(float4*)&t[node * 64 + tf * 4] = o;
        }
    }
}

// ---------------- W3 transform: T32[i] = dis[i] * (H[i] @ W3) ----------------

__global__ void transform64_32_kernel(const float* __restrict__ h, const float* __restrict__ W,
                                      const float* __restrict__ dis, float* __restrict__ t, int n) {
    __shared__ float Wt[32 * TPAD];
    __shared__ float Hs[128 * TPAD];
    const int tid = threadIdx.x;
    const int base = blockIdx.x * 128;
    for (int idx = tid; idx < 2048; idx += 256) {
        int k = idx >> 5, f = idx & 31;
        Wt[f * TPAD + k] = W[idx];
    }
    for (int idx = tid; idx < 8192; idx += 256) {
        int nn = idx >> 6, k = idx & 63;
        int node = base + nn;
        Hs[nn * TPAD + k] = (node < n) ? h[node * 64 + k] : 0.0f;
    }
    __syncthreads();
    const int tf = tid & 7;
    const int tn = tid >> 3;
    float acc[4][4] = {};
    for (int k = 0; k < 64; k += 4) {
        float4 w4[4], h4[4];
        #pragma unroll
        for (int ff = 0; ff < 4; ++ff) w4[ff] = *(const float4*)&Wt[(tf * 4 + ff) * TPAD + k];
        #pragma unroll
        for (int nn = 0; nn < 4; ++nn) h4[nn] = *(const float4*)&Hs[(tn * 4 + nn) * TPAD + k];
        #pragma unroll
        for (int nn = 0; nn < 4; ++nn)
            #pragma unroll
            for (int ff = 0; ff < 4; ++ff)
                acc[nn][ff] += h4[nn].x * w4[ff].x + h4[nn].y * w4[ff].y +
                               h4[nn].z * w4[ff].z + h4[nn].w * w4[ff].w;
    }
    #pragma unroll
    for (int nn = 0; nn < 4; ++nn) {
        int node = base + tn * 4 + nn;
        if (node < n) {
            float d = dis[node];
            float4 o = make_float4(d * acc[nn][0], d * acc[nn][1], d * acc[nn][2], d * acc[nn][3]);
            *(float4*)&t[node * 32 + tf * 4] = o;
        }
    }
}

// ---------------- readout ----------------

__device__ __forceinline__ unsigned mapf(float v) {
    unsigned u = __float_as_uint(v);
    return u ^ ((u & 0x80000000u) ? 0xFFFFFFFFu : 0x80000000u);
}

#define MAPPED_NEG_INF 0x007FFFFFu

__global__ void init_readout_kernel(float* __restrict__ gsum, unsigned* __restrict__ gmax,
                                    int* __restrict__ gcnt) {
    int idx = blockIdx.x * blockDim.x + threadIdx.x;
    if (idx < N_GRAPHS * 32) { gsum[idx] = 0.0f; gmax[idx] = MAPPED_NEG_INF; }
    if (idx < N_GRAPHS) gcnt[idx] = 0;
}

#define R_CHUNK 512
__global__ void readout_kernel(const float* __restrict__ emb, const int* __restrict__ batch,
                               float* __restrict__ gsum, unsigned* __restrict__ gmax,
                               int* __restrict__ gcnt, int n) {
    __shared__ float ssum[N_GRAPHS * 32];
    __shared__ unsigned smax[N_GRAPHS * 32];
    __shared__ int scnt[N_GRAPHS];
    const int tid = threadIdx.x;
    for (int idx = tid; idx < N_GRAPHS * 32; idx += 256) { ssum[idx] = 0.0f; smax[idx] = MAPPED_NEG_INF; }
    if (tid < N_GRAPHS) scnt[tid] = 0;
    __syncthreads();
    const int lane = tid & 31, grp = tid >> 5;
    const int start = blockIdx.x * R_CHUNK;
    const int end = min(start + R_CHUNK, n);
    for (int i = start + grp; i < end; i += 8) {
        int g = batch[i];
        float v = emb[i * 32 + lane];
        atomicAdd(&ssum[g * 32 + lane], v);
        atomicMax(&smax[g * 32 + lane], mapf(v));
        if (lane == 0) atomicAdd(&scnt[g], 1);
    }
    __syncthreads();
    for (int idx = tid; idx < N_GRAPHS * 32; idx += 256) {
        int g = idx >> 5;
        if (scnt[g] > 0) {
            atomicAdd(&gsum[idx], ssum[idx]);
            atomicMax(&gmax[idx], smax[idx]);
        }
    }
    if (tid < N_GRAPHS && scnt[tid] > 0) atomicAdd(&gcnt[tid], scnt[tid]);
}

__global__ void finalize_kernel(const float* __restrict__ gsum, const unsigned* __restrict__ gmax,
                                const int* __restrict__ gcnt, float* __restrict__ out) {
    int idx = blockIdx.x * blockDim.x + threadIdx.x;
    if (idx >= N_GRAPHS * 32) return;
    int g = idx >> 5, f = idx & 31;
    float c = fmaxf((float)gcnt[g], 1.0f);
    out[g * 64 + f] = gsum[idx] / c;
    unsigned u = gmax[idx];
    unsigned bits = (u & 0x80000000u) ? (u ^ 0x80000000u) : ~u;
    out[g * 64 + 32 + f] = __uint_as_float(bits);
}

// ---------------- launch ----------------

extern "C" void kernel_launch(void* const* d_in, const int* in_sizes, int n_in,
                              void* d_out, int out_size, void* d_ws, size_t ws_size,
                              hipStream_t stream) {
    const float* x  = (const float*)d_in[0];
    const float* W1 = (const float*)d_in[1];
    const float* b1 = (const float*)d_in[2];
    const float* W2 = (const float*)d_in[3];
    const float* b2 = (const float*)d_in[4];
    const float* W3 = (const float*)d_in[5];
    const float* b3 = (const float*)d_in[6];
    const int* edge_index = (const int*)d_in[7];
    const int* batch = (const int*)d_in[8];
    float* out = (float*)d_out;

    const int N = in_sizes[0] / 4;
    const int E = in_sizes[7] / 2;
    const int* src = edge_index;
    const int* dst = edge_index + E;
    const int nbuck = (N + 255) >> 8;        // 391
    const int nwave = nbuck * 8;             // 3128 (wave = 32 nodes)
    const int gagg = (nwave + 3) / 4;        // 782 blocks, all resident

    // workspace carve-up (256B aligned)
    char* p = (char*)d_ws;
    auto alloc = [&](size_t bytes) { void* r = (void*)p; p += (bytes + 255) & ~(size_t)255; return r; };
    float*          dis    = (float*)alloc((size_t)N * 4);
    int*            col3   = (int*)alloc((size_t)E * 4);
    unsigned short* cnt16  = (unsigned short*)alloc((size_t)nwave * NT * 2);
    int*            wstart = (int*)alloc((size_t)nwave * 4);
    float*          T      = (float*)alloc((size_t)N * 64 * 4);
    float*          H      = (float*)alloc((size_t)N * 64 * 4);
    float*          T32    = (float*)alloc((size_t)N * 32 * 4);
    int*            bcnt   = (int*)alloc((size_t)512 * 4);
    int*            bbase  = (int*)alloc((size_t)513 * 4);
    int*            bcur   = (int*)alloc((size_t)512 * 4);
    float*          gsum   = (float*)alloc((size_t)N_GRAPHS * 32 * 4);
    unsigned*       gmax   = (unsigned*)alloc((size_t)N_GRAPHS * 32 * 4);
    int*            gcnt   = (int*)alloc((size_t)N_GRAPHS * 4);
    // aliases (lifetimes disjoint, stream-ordered):
    unsigned* binned = (unsigned*)T;           // consumed by build before fused_l1 writes T
    float*    Xs     = H;                      // dead before agg<64> writes H
    float*    aggX   = H + (size_t)N * 4;      // dead before agg<64> writes H
    float*    H32    = T;                      // written after T dead (post transform64_32)
    (void)ws_size; (void)n_in; (void)out_size;

    // CSR build: bucket-binned scatter, then per-bucket (wave,tile,slot) sort
    hipMemsetAsync(bcnt, 0, 512 * 4, stream);
    bucket_hist_kernel<<<(E + EBH - 1) / EBH, 256, 0, stream>>>(dst, bcnt, E, nbuck);
    bucket_scan_kernel<<<1, 512, 0, stream>>>(bcnt, bbase, bcur, nbuck);
    binscatter_kernel<<<(E + EBC - 1) / EBC, 256, 0, stream>>>(src, dst, bcur, binned, E, nbuck);
    build_sorted_kernel<<<nbuck, 256, 0, stream>>>(binned, bbase, x, dis, Xs, col3, cnt16, wstart, N);

    // layer 1: phase-aligned aggregate Xs (4-dim) -> aggX = dis*(sum+self), then fused transform -> T
    agg_phase_kernel<4, false, false><<<gagg, 256, 0, stream>>>(Xs, col3, cnt16, wstart, dis, b1, aggX, N, nwave);
    fused_l1_kernel<<<(N + 63) / 64, 256, 0, stream>>>(aggX, W1, b1, W2, dis, T, N);
    // layer 2: phase-aligned aggregate T (64-dim) -> H = relu(dis*(sum+self)+b2)
    agg_phase_kernel<64, true, true><<<gagg, 256, 0, stream>>>(T, col3, cnt16, wstart, dis, b2, H, N, nwave);
    // W3: T32 = dis * (H @ W3)
    transform64_32_kernel<<<(N + 127) / 128, 256, 0, stream>>>(H, W3, dis, T32, N);
    // layer 3: phase-aligned aggregate T32 (32-dim) -> H32 = dis*(sum+self)+b3
    agg_phase_kernel<32, false, true><<<gagg, 256, 0, stream>>>(T32, col3, cnt16, wstart, dis, b3, H32, N, nwave);

    // readout
    init_readout_kernel<<<(N_GRAPHS * 32 + 255) / 256, 256, 0, stream>>>(gsum, gmax, gcnt);
    readout_kernel<<<(N + R_CHUNK - 1) / R_CHUNK, 256, 0, stream>>>(H32, batch, gsum, gmax, gcnt, N);
    finalize_kernel<<<(N_GRAPHS * 32 + 255) / 256, 256, 0, stream>>>(gsum, gmax, gcnt, out);
}